// Round 10
// baseline (240.287 us; speedup 1.0000x reference)
//
#include <hip/hip_runtime.h>
#include <hip/hip_bf16.h>
#include <math.h>

// NoisyTopkRouter round 10: round-9 m97-shape with the B-staging bug fixed.
// BUG WAS: global_load_lds B-staging used a wave-uniform global address; the
// global side of global_load_lds is PER-LANE (only the LDS side is implicit
// base + lane*16). Fixed by adding lane*8 shorts to the B global address.
//
// 128 tokens x 128 cols per block (grid 256 = 1 block/CU), 512 threads = 8
// waves (4m x 2n), wave = 32 tok x 64 col, 24 MFMAs/wave/chunk.
// BOTH operands staged via global_load_lds (32 KB per chunk per block,
// double-buffered, 1 barrier/chunk):
//  - A fp32 staged in MFMA-frag order (staging lane == reading granule ->
//    frag reads are lane*16 contiguous, conflict-free by construction).
//  - B prepacked hi/lo bf16 bricks (1 KB per (ntile,chunk)) staged verbatim.
// bf16x2 split (Ah*Wh + Ah*Wl + Al*Wh) as in rounds 2-8 (all passed).

#define T_TOKENS 32768
#define D_MODEL  1024
#define NE       64
#define NCOL     128
#define M_TILE   128
#define NCHUNK   32
#define CS_LD    68
#define OUT_IDX_BASE ((size_t)T_TOKENS * NE)
#define W_ELEMS  (NCOL * D_MODEL)

typedef short  bf16x8  __attribute__((ext_vector_type(8)));
typedef float  floatx4 __attribute__((ext_vector_type(4)));

__device__ __forceinline__ float softplus_f(float x) {
    return fmaxf(x, 0.f) + log1pf(expf(-fabsf(x)));
}

__device__ __forceinline__ void gload_lds16(const void* g, void* l) {
    __builtin_amdgcn_global_load_lds(
        (const __attribute__((address_space(1))) void*)g,
        (__attribute__((address_space(3))) void*)l, 16, 0, 0);
}

// 8 floats -> bf16 hi/lo frag halves (RNE hi, exact residual, RNE lo).
__device__ __forceinline__ void cvt8frag(const float4 a, const float4 b,
                                         bf16x8* hi, bf16x8* lo) {
    float v[8] = {a.x, a.y, a.z, a.w, b.x, b.y, b.z, b.w};
    int hw[4], lw[4];
    #pragma unroll
    for (int p = 0; p < 4; ++p) {
        float2 f2 = make_float2(v[2 * p], v[2 * p + 1]);
        __hip_bfloat162 h2 = __float22bfloat162_rn(f2);
        int u; __builtin_memcpy(&u, &h2, 4);
        float h0 = __uint_as_float(((unsigned)u) << 16);
        float h1 = __uint_as_float(((unsigned)u) & 0xFFFF0000u);
        float2 l2 = make_float2(v[2 * p] - h0, v[2 * p + 1] - h1);
        __hip_bfloat162 L2 = __float22bfloat162_rn(l2);
        int ul; __builtin_memcpy(&ul, &L2, 4);
        hw[p] = u; lw[p] = ul;
    }
    int4 hp = make_int4(hw[0], hw[1], hw[2], hw[3]);
    int4 lp = make_int4(lw[0], lw[1], lw[2], lw[3]);
    __builtin_memcpy(hi, &hp, 16);
    __builtin_memcpy(lo, &lp, 16);
}

// ---------------- prepack: W -> hi/lo bf16 in B-frag order ----------------
// elem = ((ntile*128 + kgrp)*16 + n16)*8 + j ; value = W[ntile*16+n16][kgrp*8+j]
// Brick (ntile t, chunk kc) = 512 shorts contiguous at offset t*16384 + kc*512.
__global__ __launch_bounds__(256) void prepack_w(
    const float* __restrict__ Wr, const float* __restrict__ Wn,
    short* __restrict__ Bh, short* __restrict__ Bl)
{
    int g   = blockIdx.x * 256 + threadIdx.x;
    int n   = g & 15;
    int kg  = (g >> 4) & 127;
    int t2  = g >> 11;
    int col = t2 * 16 + n;
    const float* src = (col < NE ? Wr + (size_t)col * D_MODEL
                                 : Wn + (size_t)(col - NE) * D_MODEL) + kg * 8;
    float4 a = *(const float4*)src;
    float4 b = *(const float4*)(src + 4);
    bf16x8 hi, lo;
    cvt8frag(a, b, &hi, &lo);
    *(bf16x8*)(Bh + (size_t)g * 8) = hi;
    *(bf16x8*)(Bl + (size_t)g * 8) = lo;
}

// ---------------- main fused kernel ----------------
__global__ __launch_bounds__(512, 1) void router_mfma(
    const float* __restrict__ A,
    const float* __restrict__ noise,
    const float* __restrict__ br,
    const float* __restrict__ bn,
    const short* __restrict__ Bh,
    const short* __restrict__ Bl,
    float* __restrict__ out)
{
    // A chunk, frag order: region (r16, h) = 64 granules of 16B; granule = lane.
    //   granule(ell) of (r16,h) = A[r16*16 + (ell&15)][8*(ell>>4) + 4h ..+3]
    __shared__ __align__(16) float Abuf[2][4096];        // 2 x 16 KB
    // B chunk: region (plane p, ntile t) = verbatim prepacked brick (granule=lane).
    __shared__ __align__(16) short Bbuf[2][8192];        // 2 x 16 KB
    __shared__ float Cs[M_TILE * CS_LD];
    __shared__ float s_p1[M_TILE], s_p2[M_TILE];
    __shared__ int   s_e1[M_TILE], s_e2[M_TILE];

    const int tid  = threadIdx.x;
    const int lane = tid & 63;
    const int wid  = tid >> 6;        // 0..7
    const int wm   = wid >> 1;        // 0..3 : tokens wm*32..+31
    const int wn   = wid & 1;         // 0..1 : route cols wn*32..+31 (+64 noise)
    const int n16  = lane & 15;
    const int quad = lane >> 4;
    const int m0   = blockIdx.x * M_TILE;

    // ---- staging assignments ----
    // A: wave wid stages row-group r16=wid (rows wid*16+n16), halves h=0,1.
    //    Per-lane global address (n16, quad per-lane). LDS side: lane*16.
    const float* gAst = A + (size_t)(m0 + wid * 16 + n16) * D_MODEL + quad * 8;
    // B: wave wid stages plane p=wid>>2, ntiles t0=(wid&3)*2 and t0+1.
    //    PER-LANE global address: + lane*8 shorts (16B per lane).  <-- THE FIX
    const int   sp  = wid >> 2;
    const int   st0 = (wid & 3) * 2;
    const short* gBst = (sp ? Bl : Bh) + (size_t)lane * 8;

    floatx4 accR[2][2], accN[2][2];   // [mf][fi]
    #pragma unroll
    for (int mf = 0; mf < 2; ++mf)
        #pragma unroll
        for (int fi = 0; fi < 2; ++fi) { accR[mf][fi] = (floatx4)0.f; accN[mf][fi] = (floatx4)0.f; }

    // ---- prologue: stage chunk 0 into buf 0 ----
    gload_lds16(gAst + 0, &Abuf[0][(wid * 2 + 0) * 256]);
    gload_lds16(gAst + 4, &Abuf[0][(wid * 2 + 1) * 256]);
    gload_lds16(gBst + (size_t)st0 * 16384,       &Bbuf[0][(sp * 8 + st0) * 512]);
    gload_lds16(gBst + (size_t)(st0 + 1) * 16384, &Bbuf[0][(sp * 8 + st0 + 1) * 512]);
    __syncthreads();

    for (int kc = 0; kc < NCHUNK; ++kc) {
        const int cur = kc & 1, nxt = cur ^ 1;

        // async-stage chunk kc+1 (lands during this iteration's compute)
        if (kc + 1 < NCHUNK) {
            const int ka = (kc + 1) * 32;
            const int kb = (kc + 1) * 512;
            gload_lds16(gAst + ka,     &Abuf[nxt][(wid * 2 + 0) * 256]);
            gload_lds16(gAst + ka + 4, &Abuf[nxt][(wid * 2 + 1) * 256]);
            gload_lds16(gBst + (size_t)st0 * 16384 + kb,       &Bbuf[nxt][(sp * 8 + st0) * 512]);
            gload_lds16(gBst + (size_t)(st0 + 1) * 16384 + kb, &Bbuf[nxt][(sp * 8 + st0 + 1) * 512]);
        }

        // A frags: fp32 from LDS (contiguous lane*16), convert to hi/lo bf16
        bf16x8 ah[2], al[2];
        #pragma unroll
        for (int mf = 0; mf < 2; ++mf) {
            const int r16 = wm * 2 + mf;
            float4 f0 = *(const float4*)&Abuf[cur][(r16 * 2 + 0) * 256 + lane * 4];
            float4 f1 = *(const float4*)&Abuf[cur][(r16 * 2 + 1) * 256 + lane * 4];
            cvt8frag(f0, f1, &ah[mf], &al[mf]);
        }

        // B frags (contiguous lane*8 shorts per brick)
        bf16x8 bhR[2], blR[2], bhN[2], blN[2];
        #pragma unroll
        for (int fi = 0; fi < 2; ++fi) {
            const int tR = 2 * wn + fi;
            const int tN = 4 + 2 * wn + fi;
            bhR[fi] = *(const bf16x8*)&Bbuf[cur][(0 * 8 + tR) * 512 + lane * 8];
            blR[fi] = *(const bf16x8*)&Bbuf[cur][(1 * 8 + tR) * 512 + lane * 8];
            bhN[fi] = *(const bf16x8*)&Bbuf[cur][(0 * 8 + tN) * 512 + lane * 8];
            blN[fi] = *(const bf16x8*)&Bbuf[cur][(1 * 8 + tN) * 512 + lane * 8];
        }

        // 24 MFMAs (8 independent chains, depth 3)
        #pragma unroll
        for (int mf = 0; mf < 2; ++mf)
            #pragma unroll
            for (int fi = 0; fi < 2; ++fi) {
                accR[mf][fi] = __builtin_amdgcn_mfma_f32_16x16x32_bf16(ah[mf], bhR[fi], accR[mf][fi], 0, 0, 0);
                accR[mf][fi] = __builtin_amdgcn_mfma_f32_16x16x32_bf16(ah[mf], blR[fi], accR[mf][fi], 0, 0, 0);
                accR[mf][fi] = __builtin_amdgcn_mfma_f32_16x16x32_bf16(al[mf], bhR[fi], accR[mf][fi], 0, 0, 0);
                accN[mf][fi] = __builtin_amdgcn_mfma_f32_16x16x32_bf16(ah[mf], bhN[fi], accN[mf][fi], 0, 0, 0);
                accN[mf][fi] = __builtin_amdgcn_mfma_f32_16x16x32_bf16(ah[mf], blN[fi], accN[mf][fi], 0, 0, 0);
                accN[mf][fi] = __builtin_amdgcn_mfma_f32_16x16x32_bf16(al[mf], bhN[fi], accN[mf][fi], 0, 0, 0);
            }

        __syncthreads();   // staging(kc+1) drained; all reads of cur done
    }

    // ---- lane-local fuse: noisy = route + noise * softplus(noise_logit) ----
    // D layout: col = lane&15, row = quad*4 + r
    #pragma unroll
    for (int fi = 0; fi < 2; ++fi) {
        const int e = wn * 32 + fi * 16 + n16;
        float brv = br[e], bnv = bn[e];
        #pragma unroll
        for (int mf = 0; mf < 2; ++mf)
            #pragma unroll
            for (int rr = 0; rr < 4; ++rr) {
                const int t = wm * 32 + mf * 16 + quad * 4 + rr;
                float nz    = noise[(size_t)(m0 + t) * NE + e];
                float route = accR[mf][fi][rr] + brv;
                float nl    = accN[mf][fi][rr] + bnv;
                Cs[t * CS_LD + e] = fmaf(nz, softplus_f(nl), route);
            }
    }
    __syncthreads();

    // ---- top-2 + softmax (one thread per token; in-order scan = stable ties) ----
    if (tid < M_TILE) {
        const int t = tid;
        float v1 = -INFINITY, v2 = -INFINITY;
        int e1 = 0, e2 = 0;
        #pragma unroll
        for (int e4 = 0; e4 < 16; ++e4) {
            float4 q = *(const float4*)&Cs[t * CS_LD + e4 * 4];
            float qa[4] = {q.x, q.y, q.z, q.w};
            #pragma unroll
            for (int c = 0; c < 4; ++c) {
                float v = qa[c];
                int e = e4 * 4 + c;
                if (v > v1) { v2 = v1; e2 = e1; v1 = v; e1 = e; }
                else if (v > v2) { v2 = v; e2 = e; }
            }
        }
        float ex = expf(v2 - v1);
        float denom = 1.f + ex;
        s_p1[t] = 1.f / denom;
        s_p2[t] = ex / denom;
        s_e1[t] = e1;
        s_e2[t] = e2;
        float2 iv = make_float2((float)e1, (float)e2);
        *(float2*)(out + OUT_IDX_BASE + (size_t)(m0 + t) * 2) = iv;
    }
    __syncthreads();

    // ---- coalesced scatter of router_output [128 tokens x 64 experts] ----
    #pragma unroll
    for (int i = 0; i < 4; ++i) {
        int gi = i * 512 + tid;       // 0..2047 float4s
        int t  = gi >> 4;
        int e0 = (gi & 15) * 4;
        float p1 = s_p1[t], p2 = s_p2[t];
        int   e1 = s_e1[t], e2 = s_e2[t];
        float4 v;
        v.x = (e0 + 0 == e1) ? p1 : ((e0 + 0 == e2) ? p2 : 0.f);
        v.y = (e0 + 1 == e1) ? p1 : ((e0 + 1 == e2) ? p2 : 0.f);
        v.z = (e0 + 2 == e1) ? p1 : ((e0 + 2 == e2) ? p2 : 0.f);
        v.w = (e0 + 3 == e1) ? p1 : ((e0 + 3 == e2) ? p2 : 0.f);
        *(float4*)(out + (size_t)(m0 + t) * NE + e0) = v;
    }
}

extern "C" void kernel_launch(void* const* d_in, const int* in_sizes, int n_in,
                              void* d_out, int out_size, void* d_ws, size_t ws_size,
                              hipStream_t stream) {
    const float* A     = (const float*)d_in[0];
    const float* noise = (const float*)d_in[1];
    const float* Wr    = (const float*)d_in[2];
    const float* br    = (const float*)d_in[3];
    const float* Wn    = (const float*)d_in[4];
    const float* bn    = (const float*)d_in[5];
    float* out = (float*)d_out;

    short* Bh = (short*)d_ws;
    short* Bl = Bh + W_ELEMS;

    prepack_w<<<dim3(W_ELEMS / 8 / 256), dim3(256), 0, stream>>>(Wr, Wn, Bh, Bl);
    router_mfma<<<dim3(T_TOKENS / M_TILE), dim3(512), 0, stream>>>(A, noise, br, bn, Bh, Bl, out);
}

// Round 11
// 229.943 us; speedup vs baseline: 1.0450x; 1.0450x over previous
//
#include <hip/hip_runtime.h>
#include <hip/hip_bf16.h>
#include <math.h>

// NoisyTopkRouter FINAL-candidate (= round-6 structure, best measured:
// dispatch ~80 us, bench 229.3 us). bf16x2-split MFMA, M=64 per wave.
// - Each of 4 waves computes ALL 64 rows x its (route ntile w, noise ntile w+4)
//   -> minimal B-fragment VMEM; lane-local route/noise fuse in the epilogue.
// - A fp32 -> hi/lo bf16 once per block into double-buffered LDS (frag order,
//   conflict-free); raw-A register pipeline 2 iterations deep; B prepacked in
//   frag order in d_ws (L1/L2-hot), register-prefetched 1 chunk ahead.
// - Plateau note (rounds 2-10): seven structures (scalar/async staging,
//   0-32 barriers, 8-16 waves/CU, 1.3K-2.5K VMEM instrs/CU) all land
//   80-95 us with every pipe <25% busy; counter-implied effective clock
//   ~0.5-0.8 GHz (DVFS-throttled low-duty dispatch). This kernel is the
//   empirical minimum of that family.

#define T_TOKENS 32768
#define D_MODEL  1024
#define NE       64
#define NCOL     128
#define M_TILE   64
#define NCHUNK   32
#define CS_LD    68
#define OUT_IDX_BASE ((size_t)T_TOKENS * NE)
#define W_ELEMS  (NCOL * D_MODEL)

typedef short  bf16x8  __attribute__((ext_vector_type(8)));
typedef float  floatx4 __attribute__((ext_vector_type(4)));

__device__ __forceinline__ float softplus_f(float x) {
    return fmaxf(x, 0.f) + log1pf(expf(-fabsf(x)));
}

// 8 floats -> packed bf16 hi (int4) + bf16 lo (int4). RNE hi, exact residual,
// RNE lo — numerics identical to all passing rounds.
__device__ __forceinline__ void cvt8(const float4 a, const float4 b,
                                     int4* hi, int4* lo) {
    float v[8] = {a.x, a.y, a.z, a.w, b.x, b.y, b.z, b.w};
    int hw[4], lw[4];
    #pragma unroll
    for (int p = 0; p < 4; ++p) {
        float2 f2 = make_float2(v[2 * p], v[2 * p + 1]);
        __hip_bfloat162 h2 = __float22bfloat162_rn(f2);
        int u; __builtin_memcpy(&u, &h2, 4);
        float h0 = __uint_as_float(((unsigned)u) << 16);
        float h1 = __uint_as_float(((unsigned)u) & 0xFFFF0000u);
        float2 l2 = make_float2(v[2 * p] - h0, v[2 * p + 1] - h1);
        __hip_bfloat162 L2 = __float22bfloat162_rn(l2);
        int ul; __builtin_memcpy(&ul, &L2, 4);
        hw[p] = u; lw[p] = ul;
    }
    *hi = make_int4(hw[0], hw[1], hw[2], hw[3]);
    *lo = make_int4(lw[0], lw[1], lw[2], lw[3]);
}

// ---------------- prepack: W -> hi/lo bf16 in B-frag order ----------------
// elem index = ((ntile*128 + kgrp)*16 + n16)*8 + j ; value = W[ntile*16+n16][kgrp*8+j]
__global__ __launch_bounds__(256) void prepack_w(
    const float* __restrict__ Wr, const float* __restrict__ Wn,
    short* __restrict__ Bh, short* __restrict__ Bl)
{
    int g   = blockIdx.x * 256 + threadIdx.x;
    int n   = g & 15;
    int kg  = (g >> 4) & 127;
    int t2  = g >> 11;
    int col = t2 * 16 + n;
    const float* src = (col < NE ? Wr + (size_t)col * D_MODEL
                                 : Wn + (size_t)(col - NE) * D_MODEL) + kg * 8;
    float4 a = *(const float4*)src;
    float4 b = *(const float4*)(src + 4);
    int4 hi, lo;
    cvt8(a, b, &hi, &lo);
    *(int4*)(Bh + (size_t)g * 8) = hi;
    *(int4*)(Bl + (size_t)g * 8) = lo;
}

// ---------------- main fused kernel ----------------
__global__ __launch_bounds__(256, 2) void router_mfma(
    const float* __restrict__ A,
    const float* __restrict__ noise,
    const float* __restrict__ br,
    const float* __restrict__ bn,
    const short* __restrict__ Bh,
    const short* __restrict__ Bl,
    float* __restrict__ out)
{
    __shared__ __align__(16) short Ah[2][M_TILE * 32];
    __shared__ __align__(16) short Al[2][M_TILE * 32];
    __shared__ float Cs[M_TILE * CS_LD];
    __shared__ float s_p1[M_TILE], s_p2[M_TILE];
    __shared__ int   s_e1[M_TILE], s_e2[M_TILE];

    const int tid  = threadIdx.x;
    const int lane = tid & 63;
    const int wid  = tid >> 6;   // wave: route ntile wid, noise ntile wid+4
    const int n16  = lane & 15;
    const int quad = lane >> 4;
    const int m0   = blockIdx.x * M_TILE;

    // staging: row r = tid&63, k-half kh = tid>>6 -> k = kh*8..kh*8+7 (32B/thread)
    const int r  = tid & 63;
    const int kh = tid >> 6;
    const float* pA = A + (size_t)(m0 + r) * D_MODEL + kh * 8;
    const int sBase = (kh * M_TILE + r) * 8;   // frag-order elem base, 16B aligned

    const int bBaseR = ((wid * 128 + quad) * 16 + n16) * 8;
    const int bBaseN = (((4 + wid) * 128 + quad) * 16 + n16) * 8;

    floatx4 acc[4][2];
    #pragma unroll
    for (int i = 0; i < 4; ++i) { acc[i][0] = (floatx4)0.f; acc[i][1] = (floatx4)0.f; }

    // ---- prologue: stage chunk 0; B(0) into regs; raw A for chunks 1,2 ----
    {
        float4 a0 = *(const float4*)pA;
        float4 a1 = *(const float4*)(pA + 4);
        int4 hi, lo;
        cvt8(a0, a1, &hi, &lo);
        *(int4*)&Ah[0][sBase] = hi;
        *(int4*)&Al[0][sBase] = lo;
    }
    bf16x8 bhR, blR, bhN, blN;
    bhR = *(const bf16x8*)(Bh + bBaseR);
    blR = *(const bf16x8*)(Bl + bBaseR);
    bhN = *(const bf16x8*)(Bh + bBaseN);
    blN = *(const bf16x8*)(Bl + bBaseN);
    float4 aP1a = *(const float4*)(pA + 32), aP1b = *(const float4*)(pA + 36);
    float4 aP2a = *(const float4*)(pA + 64), aP2b = *(const float4*)(pA + 68);
    __syncthreads();

    for (int kc = 0; kc < NCHUNK; ++kc) {
        const int cur = kc & 1, nxt = cur ^ 1;

        // raw A for chunk kc+3 (deepest slack)
        float4 f0, f1;
        if (kc + 3 < NCHUNK) {
            f0 = *(const float4*)(pA + (kc + 3) * 32);
            f1 = *(const float4*)(pA + (kc + 3) * 32 + 4);
        }
        // B for chunk kc+1
        bf16x8 bhRn, blRn, bhNn, blNn;
        if (kc + 1 < NCHUNK) {
            int o = (kc + 1) * 512;
            bhRn = *(const bf16x8*)(Bh + bBaseR + o);
            blRn = *(const bf16x8*)(Bl + bBaseR + o);
            bhNn = *(const bf16x8*)(Bh + bBaseN + o);
            blNn = *(const bf16x8*)(Bl + bBaseN + o);
        }

        // A frags (4 m-frags, conflict-free contiguous 16B/lane)
        bf16x8 afh[4], afl[4];
        #pragma unroll
        for (int mf = 0; mf < 4; ++mf) {
            int g = (quad * M_TILE + mf * 16 + n16) * 8;
            afh[mf] = *(const bf16x8*)&Ah[cur][g];
            afl[mf] = *(const bf16x8*)&Al[cur][g];
        }

        // convert + stage chunk kc+1 (raw loaded 2 iterations ago)
        if (kc + 1 < NCHUNK) {
            int4 hi, lo;
            cvt8(aP1a, aP1b, &hi, &lo);
            *(int4*)&Ah[nxt][sBase] = hi;
            *(int4*)&Al[nxt][sBase] = lo;
        }

        // 24 MFMAs (8 independent acc chains, depth 3)
        #pragma unroll
        for (int mf = 0; mf < 4; ++mf) {
            acc[mf][0] = __builtin_amdgcn_mfma_f32_16x16x32_bf16(afh[mf], bhR, acc[mf][0], 0, 0, 0);
            acc[mf][0] = __builtin_amdgcn_mfma_f32_16x16x32_bf16(afh[mf], blR, acc[mf][0], 0, 0, 0);
            acc[mf][0] = __builtin_amdgcn_mfma_f32_16x16x32_bf16(afl[mf], bhR, acc[mf][0], 0, 0, 0);
            acc[mf][1] = __builtin_amdgcn_mfma_f32_16x16x32_bf16(afh[mf], bhN, acc[mf][1], 0, 0, 0);
            acc[mf][1] = __builtin_amdgcn_mfma_f32_16x16x32_bf16(afh[mf], blN, acc[mf][1], 0, 0, 0);
            acc[mf][1] = __builtin_amdgcn_mfma_f32_16x16x32_bf16(afl[mf], bhN, acc[mf][1], 0, 0, 0);
        }

        __syncthreads();

        aP1a = aP2a; aP1b = aP2b; aP2a = f0; aP2b = f1;
        bhR = bhRn; blR = blRn; bhN = bhNn; blN = blNn;
    }

    // ---- lane-local fuse: noisy = route + noise * softplus(noise_logit) ----
    // D layout: col = lane&15, row = quad*4 + r
    {
        int e = wid * 16 + n16;
        float brv = br[e], bnv = bn[e];
        #pragma unroll
        for (int mf = 0; mf < 4; ++mf)
            #pragma unroll
            for (int rr = 0; rr < 4; ++rr) {
                int t = mf * 16 + quad * 4 + rr;
                float nz    = noise[(size_t)(m0 + t) * NE + e];
                float route = acc[mf][0][rr] + brv;
                float nl    = acc[mf][1][rr] + bnv;
                Cs[t * CS_LD + e] = fmaf(nz, softplus_f(nl), route);
            }
    }
    __syncthreads();

    // ---- top-2 + softmax (one thread per token; in-order scan = stable ties) ----
    if (tid < M_TILE) {
        const int t = tid;
        float v1 = -INFINITY, v2 = -INFINITY;
        int e1 = 0, e2 = 0;
        #pragma unroll
        for (int e4 = 0; e4 < 16; ++e4) {
            float4 q = *(const float4*)&Cs[t * CS_LD + e4 * 4];
            float qa[4] = {q.x, q.y, q.z, q.w};
            #pragma unroll
            for (int c = 0; c < 4; ++c) {
                float v = qa[c];
                int e = e4 * 4 + c;
                if (v > v1) { v2 = v1; e2 = e1; v1 = v; e1 = e; }
                else if (v > v2) { v2 = v; e2 = e; }
            }
        }
        float ex = expf(v2 - v1);
        float denom = 1.f + ex;
        s_p1[t] = 1.f / denom;
        s_p2[t] = ex / denom;
        s_e1[t] = e1;
        s_e2[t] = e2;
        float2 iv = make_float2((float)e1, (float)e2);
        *(float2*)(out + OUT_IDX_BASE + (size_t)(m0 + t) * 2) = iv;
    }
    __syncthreads();

    // ---- coalesced scatter of router_output [64 tokens x 64 experts] ----
    #pragma unroll
    for (int i = 0; i < 4; ++i) {
        int gi = i * 256 + tid;       // 0..1023 float4s
        int t  = gi >> 4;
        int e0 = (gi & 15) * 4;
        float p1 = s_p1[t], p2 = s_p2[t];
        int   e1 = s_e1[t], e2 = s_e2[t];
        float4 v;
        v.x = (e0 + 0 == e1) ? p1 : ((e0 + 0 == e2) ? p2 : 0.f);
        v.y = (e0 + 1 == e1) ? p1 : ((e0 + 1 == e2) ? p2 : 0.f);
        v.z = (e0 + 2 == e1) ? p1 : ((e0 + 2 == e2) ? p2 : 0.f);
        v.w = (e0 + 3 == e1) ? p1 : ((e0 + 3 == e2) ? p2 : 0.f);
        *(float4*)(out + (size_t)(m0 + t) * NE + e0) = v;
    }
}

extern "C" void kernel_launch(void* const* d_in, const int* in_sizes, int n_in,
                              void* d_out, int out_size, void* d_ws, size_t ws_size,
                              hipStream_t stream) {
    const float* A     = (const float*)d_in[0];
    const float* noise = (const float*)d_in[1];
    const float* Wr    = (const float*)d_in[2];
    const float* br    = (const float*)d_in[3];
    const float* Wn    = (const float*)d_in[4];
    const float* bn    = (const float*)d_in[5];
    float* out = (float*)d_out;

    short* Bh = (short*)d_ws;
    short* Bl = Bh + W_ELEMS;

    prepack_w<<<dim3(W_ELEMS / 8 / 256), dim3(256), 0, stream>>>(Wr, Wn, Bh, Bl);
    router_mfma<<<dim3(T_TOKENS / M_TILE), dim3(256), 0, stream>>>(A, noise, br, bn, Bh, Bl, out);
}